// Round 6
// baseline (251.804 us; speedup 1.0000x reference)
//
#include <hip/hip_runtime.h>
#include <hip/hip_bf16.h>

// ---------- types ----------
typedef __attribute__((ext_vector_type(4))) float  f32x4;
typedef __attribute__((ext_vector_type(8))) short  bf16x8;   // 8 bf16 in 4 VGPRs
typedef __attribute__((ext_vector_type(8))) unsigned short u16x8;

union FU { int w[4]; bf16x8 v; };

__device__ __forceinline__ unsigned short f2bf(float f) {
    union { float f; unsigned u; } v; v.f = f;
    unsigned u = v.u;
    unsigned r = u + 0x7fffu + ((u >> 16) & 1u);   // round-to-nearest-even
    return (unsigned short)(r >> 16);
}

__device__ __forceinline__ unsigned cvtpk(float lo, float hi) {
    unsigned r;
    asm("v_cvt_pk_bf16_f32 %0, %1, %2" : "=v"(r) : "v"(lo), "v"(hi));
    return r;
}

__device__ __forceinline__ int selshfl(unsigned lo, unsigned hiw, int srcLane, bool hi) {
    int a = __shfl((int)lo, srcLane, 64);
    int b = __shfl((int)hiw, srcLane, 64);
    return hi ? b : a;
}

__device__ __forceinline__ void gload16(const void* g, void* l) {
    __builtin_amdgcn_global_load_lds((const __attribute__((address_space(1))) unsigned*)g,
                                     (__attribute__((address_space(3))) unsigned*)l, 16, 0, 0);
}

// ---------- problem constants ----------
// B=2, T=64, CH=512, Hs=24, Ws=24, HW=576, P=1152, DIM=256, HEADS=8, HD=32
// xb layout: p-major, xb[(p*64 + t)*256 + c]

// ---------- K0: weights fp32 -> bf16 ----------
__global__ void cvt_weights(const float* __restrict__ qkv_w, const float* __restrict__ proj_w,
                            unsigned short* __restrict__ wq, unsigned short* __restrict__ wp) {
    int i = blockIdx.x * 256 + threadIdx.x;          // 262144 total
    if (i < 196608) wq[i] = f2bf(qkv_w[i]);
    else            wp[i - 196608] = f2bf(proj_w[i - 196608]);
}

// ---------- K2: transpose b-half -> xb[(p*64+t)*256 + c] bf16; also copies a-half ----------
__global__ __launch_bounds__(256) void transpose_b(const float* __restrict__ x,
                                                   unsigned short* __restrict__ xb,
                                                   float* __restrict__ outp) {
    __shared__ unsigned short tile[256][72];
    const int bt  = blockIdx.x;                       // b*64+t
    const int hw0 = blockIdx.y * 64;
    const int tid = threadIdx.x;
    // a-half copy: 256 ch x 64 hw of this slab
    {
        const size_t slab = (size_t)bt * 294912;      // 512*576
        #pragma unroll
        for (int it = 0; it < 16; ++it) {
            int idx = it * 256 + tid;
            int ch  = idx >> 4;
            int off = (idx & 15) * 4;
            size_t o = slab + (size_t)ch * 576 + hw0 + off;
            *(float4*)(outp + o) = *(const float4*)(x + o);
        }
    }
    const float* src = x + ((size_t)bt * 512 + 256) * 576 + hw0;
    const int c_sub = tid >> 4, l16 = tid & 15;
    #pragma unroll
    for (int it = 0; it < 16; ++it) {
        int cc = it * 16 + c_sub;
        const float4 v = *(const float4*)(src + (size_t)cc * 576 + l16 * 4);
        tile[cc][l16 * 4 + 0] = f2bf(v.x);
        tile[cc][l16 * 4 + 1] = f2bf(v.y);
        tile[cc][l16 * 4 + 2] = f2bf(v.z);
        tile[cc][l16 * 4 + 3] = f2bf(v.w);
    }
    __syncthreads();
    const int row = tid >> 2;                 // hw within tile
    const int cs  = (tid & 3) * 64;
    const int b = bt >> 6, t = bt & 63;
    size_t m = ((size_t)(b * 576 + hw0 + row)) * 64 + t;   // p-major
    unsigned short* dst = xb + m * 256 + cs;
    #pragma unroll
    for (int q = 0; q < 8; ++q) {
        u16x8 v;
        #pragma unroll
        for (int u = 0; u < 8; ++u) v[u] = tile[cs + q * 8 + u][row];
        *(u16x8*)(dst + q * 8) = v;
    }
}

// ---------- K3: fused qkv + attention + proj, one block per pixel ----------
// 512 threads = 8 waves; wave w owns head w. LDS 78 KB -> 2 blocks/CU = 4 waves/EU.
// waves_per_eu(4,4): pin allocator at the 128-VGPR / 4-wave point (LDS caps there anyway).
__global__ __launch_bounds__(512) __attribute__((amdgpu_waves_per_eu(4, 4)))
void fused_block(
    const unsigned short* __restrict__ xb,
    const unsigned short* __restrict__ wqkv,   // [768][256] bf16
    const unsigned short* __restrict__ wproj,  // [256][256] bf16
    const float* __restrict__ qkv_b,
    const float* __restrict__ proj_b,
    const float* __restrict__ rpb,
    float* __restrict__ out)
{
    __shared__ unsigned short xs[16384];        // 64 t-rows x 256 c (swizzled 16B units); reused as att
    __shared__ unsigned short VtAll[256 * 88];  // V^T[d][t], row stride 88
    __shared__ float bias_s[8][64];             // bias_s[h][d], d = j-i+63 <= 63 for unmasked

    const int tid  = threadIdx.x;
    const int lane = tid & 63, w = tid >> 6;
    const int c = lane & 15, g = lane >> 4;
    const int c7 = c & 7;
    const bool hi = g >= 2;                     // a2/jt-select for the g-group shuffle
    const int lA = c + 16 * ((2 * g) & 3);      // source lane for frag words 0,1
    const int lB = c + 16 * ((2 * g + 1) & 3);  // source lane for frag words 2,3
    const int bid = blockIdx.x;
    const int p  = (bid & 7) * 144 + (bid >> 3);   // XCD-contiguous pixels
    const int b  = p / 576, hw = p % 576;

    // ---- stage xs (32 KB), source pre-swizzled so linear LDS holds swizzled rows
    const unsigned short* src = xb + (size_t)p * 16384;
    #pragma unroll
    for (int it = 0; it < 4; ++it) {
        int U = it * 512 + tid;
        int r = U >> 5, u = U & 31;
        gload16(src + r * 256 + ((u ^ (r & 7)) << 3), &xs[U << 3]);
    }
    bias_s[tid & 7][tid >> 3] = rpb[tid];       // rows 0..63 of rpb -> [h][d]
    __syncthreads();

    const float* bias_w = bias_s[w];

    // ================= pass 1: V  (acc -> VtAll, own rows only) =================
    {
        f32x4 acc[2][4] = {};
        #pragma unroll
        for (int ks = 0; ks < 8; ++ks) {
            bf16x8 bx[4], af[2];
            #pragma unroll
            for (int b2 = 0; b2 < 4; ++b2)
                bx[b2] = *(const bf16x8*)(&xs[(b2 * 16 + c) * 256 + (((ks * 4 + g) ^ c7) << 3)]);
            #pragma unroll
            for (int a2 = 0; a2 < 2; ++a2)
                af[a2] = *(const bf16x8*)(wqkv + (size_t)(512 + w * 32 + a2 * 16 + c) * 256 + ks * 32 + g * 8);
            #pragma unroll
            for (int a2 = 0; a2 < 2; ++a2)
                #pragma unroll
                for (int b2 = 0; b2 < 4; ++b2)
                    acc[a2][b2] = __builtin_amdgcn_mfma_f32_16x16x32_bf16(af[a2], bx[b2], acc[a2][b2], 0, 0, 0);
        }
        #pragma unroll
        for (int a2 = 0; a2 < 2; ++a2) {
            float4 bv = *(const float4*)(qkv_b + 512 + w * 32 + a2 * 16 + g * 4);
            #pragma unroll
            for (int b2 = 0; b2 < 4; ++b2) {
                int t = b2 * 16 + c;
                VtAll[(w * 32 + a2 * 16 + g * 4 + 0) * 88 + t] = f2bf(acc[a2][b2][0] + bv.x);
                VtAll[(w * 32 + a2 * 16 + g * 4 + 1) * 88 + t] = f2bf(acc[a2][b2][1] + bv.y);
                VtAll[(w * 32 + a2 * 16 + g * 4 + 2) * 88 + t] = f2bf(acc[a2][b2][2] + bv.z);
                VtAll[(w * 32 + a2 * 16 + g * 4 + 3) * 88 + t] = f2bf(acc[a2][b2][3] + bv.w);
            }
        }
    }

    // ================= pass 2: K and Q together (stay in registers, packed) =================
    unsigned kpk[2][4][2], qpk[2][4][2];   // [a2][b2][pair]: packed bf16 pairs over r
    {
        f32x4 ak[2][4] = {}, aq[2][4] = {};
        #pragma unroll
        for (int ks = 0; ks < 8; ++ks) {
            bf16x8 bx[4], afk[2], afq[2];
            #pragma unroll
            for (int b2 = 0; b2 < 4; ++b2)
                bx[b2] = *(const bf16x8*)(&xs[(b2 * 16 + c) * 256 + (((ks * 4 + g) ^ c7) << 3)]);
            #pragma unroll
            for (int a2 = 0; a2 < 2; ++a2) {
                afk[a2] = *(const bf16x8*)(wqkv + (size_t)(256 + w * 32 + a2 * 16 + c) * 256 + ks * 32 + g * 8);
                afq[a2] = *(const bf16x8*)(wqkv + (size_t)(      w * 32 + a2 * 16 + c) * 256 + ks * 32 + g * 8);
            }
            #pragma unroll
            for (int a2 = 0; a2 < 2; ++a2)
                #pragma unroll
                for (int b2 = 0; b2 < 4; ++b2) {
                    ak[a2][b2] = __builtin_amdgcn_mfma_f32_16x16x32_bf16(afk[a2], bx[b2], ak[a2][b2], 0, 0, 0);
                    aq[a2][b2] = __builtin_amdgcn_mfma_f32_16x16x32_bf16(afq[a2], bx[b2], aq[a2][b2], 0, 0, 0);
                }
        }
        #pragma unroll
        for (int a2 = 0; a2 < 2; ++a2) {
            float4 bk = *(const float4*)(qkv_b + 256 + w * 32 + a2 * 16 + g * 4);
            float4 bq = *(const float4*)(qkv_b +       w * 32 + a2 * 16 + g * 4);
            #pragma unroll
            for (int b2 = 0; b2 < 4; ++b2) {
                kpk[a2][b2][0] = cvtpk(ak[a2][b2][0] + bk.x, ak[a2][b2][1] + bk.y);
                kpk[a2][b2][1] = cvtpk(ak[a2][b2][2] + bk.z, ak[a2][b2][3] + bk.w);
                qpk[a2][b2][0] = cvtpk(aq[a2][b2][0] + bq.x, aq[a2][b2][1] + bq.y);
                qpk[a2][b2][1] = cvtpk(aq[a2][b2][2] + bq.z, aq[a2][b2][3] + bq.w);
            }
        }
    }

    // ---- build K fragments once (kpk dies here) ----
    bf16x8 kf[4];
    #pragma unroll
    for (int t = 0; t < 4; ++t) {
        FU f;
        f.w[0] = selshfl(kpk[0][t][0], kpk[1][t][0], lA, hi);
        f.w[1] = selshfl(kpk[0][t][1], kpk[1][t][1], lA, hi);
        f.w[2] = selshfl(kpk[0][t][0], kpk[1][t][0], lB, hi);
        f.w[3] = selshfl(kpk[0][t][1], kpk[1][t][1], lB, hi);
        kf[t] = f.v;
    }
    // ---- V^T fragments ----
    bf16x8 vf[2][2];
    #pragma unroll
    for (int dt = 0; dt < 2; ++dt)
        #pragma unroll
        for (int kk = 0; kk < 2; ++kk)
            vf[dt][kk] = *(const bf16x8*)(&VtAll[(w * 32 + dt * 16 + c) * 88 + kk * 32 + g * 8]);

    // ================= per-it column: QK^T -> softmax -> PV (low register liveness) =================
    const float scale = 0.17677669529663687f;  // 1/sqrt(32)
    f32x4 O[2][4];   // [dt][it]: value (d = 16dt+4g+r, i = 16it+c)
    #pragma unroll
    for (int dt = 0; dt < 2; ++dt)
        #pragma unroll
        for (int it = 0; it < 4; ++it)
            O[dt][it] = f32x4{0.f, 0.f, 0.f, 0.f};

    #pragma unroll
    for (int it = 0; it < 4; ++it) {
        // Q fragment for this column
        FU fq;
        fq.w[0] = selshfl(qpk[0][it][0], qpk[1][it][0], lA, hi);
        fq.w[1] = selshfl(qpk[0][it][1], qpk[1][it][1], lA, hi);
        fq.w[2] = selshfl(qpk[0][it][0], qpk[1][it][0], lB, hi);
        fq.w[3] = selshfl(qpk[0][it][1], qpk[1][it][1], lB, hi);
        // S^T column: Sc[jt], (j = 16jt+4g+r, i = 16it+c)
        f32x4 Sc[4];
        #pragma unroll
        for (int jt = 0; jt < 4; ++jt) Sc[jt] = f32x4{0.f, 0.f, 0.f, 0.f};
        __builtin_amdgcn_s_setprio(1);
        #pragma unroll
        for (int jt = 0; jt < 4; ++jt)
            Sc[jt] = __builtin_amdgcn_mfma_f32_16x16x32_bf16(kf[jt], fq.v, Sc[jt], 0, 0, 0);
        __builtin_amdgcn_s_setprio(0);
        // softmax on column (row i spread over 4 g-lanes)
        float rs = 0.f;
        const int i = it * 16 + c;
        #pragma unroll
        for (int jt = 0; jt < 4; ++jt)
            #pragma unroll
            for (int r = 0; r < 4; ++r) {
                int j = jt * 16 + 4 * g + r;
                int d = j - i + 63; d = d > 63 ? 63 : d;
                float v = Sc[jt][r] * scale + bias_w[d];
                float e = (j > i) ? 0.f : __expf(v);
                Sc[jt][r] = e;
                rs += e;
            }
        rs += __shfl_xor(rs, 16, 64);
        rs += __shfl_xor(rs, 32, 64);
        float inv = 1.0f / rs;
        unsigned pc[4][2];
        #pragma unroll
        for (int jt = 0; jt < 4; ++jt) {
            pc[jt][0] = cvtpk(Sc[jt][0] * inv, Sc[jt][1] * inv);
            pc[jt][1] = cvtpk(Sc[jt][2] * inv, Sc[jt][3] * inv);
        }
        // PV for this column
        #pragma unroll
        for (int kk = 0; kk < 2; ++kk) {
            FU pf;
            pf.w[0] = selshfl(pc[2 * kk][0], pc[2 * kk + 1][0], lA, hi);
            pf.w[1] = selshfl(pc[2 * kk][1], pc[2 * kk + 1][1], lA, hi);
            pf.w[2] = selshfl(pc[2 * kk][0], pc[2 * kk + 1][0], lB, hi);
            pf.w[3] = selshfl(pc[2 * kk][1], pc[2 * kk + 1][1], lB, hi);
            __builtin_amdgcn_s_setprio(1);
            #pragma unroll
            for (int dt = 0; dt < 2; ++dt)
                O[dt][it] = __builtin_amdgcn_mfma_f32_16x16x32_bf16(vf[dt][kk], pf.v, O[dt][it], 0, 0, 0);
            __builtin_amdgcn_s_setprio(0);
        }
    }

    __syncthreads();   // all waves done reading xs
    // ---- O -> att (xs region, swizzled units) ----
    #pragma unroll
    for (int dt = 0; dt < 2; ++dt)
        #pragma unroll
        for (int it = 0; it < 4; ++it)
            #pragma unroll
            for (int r = 0; r < 4; ++r) {
                int t  = it * 16 + c;
                int cg = w * 32 + dt * 16 + 4 * g + r;
                xs[t * 256 + ((((cg >> 3) ^ (t & 7)) << 3) | (cg & 7))] = f2bf(O[dt][it][r]);
            }
    __syncthreads();

    // ================= proj: D[n][t], A = Wp rows (wave's 32 n), B = att rows =================
    f32x4 ap[2][4] = {};
    #pragma unroll
    for (int ks = 0; ks < 8; ++ks) {
        bf16x8 af[2], bx[4];
        #pragma unroll
        for (int a2 = 0; a2 < 2; ++a2)
            af[a2] = *(const bf16x8*)(wproj + (size_t)(w * 32 + a2 * 16 + c) * 256 + ks * 32 + g * 8);
        #pragma unroll
        for (int b2 = 0; b2 < 4; ++b2)
            bx[b2] = *(const bf16x8*)(&xs[(b2 * 16 + c) * 256 + (((ks * 4 + g) ^ c7) << 3)]);
        #pragma unroll
        for (int a2 = 0; a2 < 2; ++a2)
            #pragma unroll
            for (int b2 = 0; b2 < 4; ++b2)
                ap[a2][b2] = __builtin_amdgcn_mfma_f32_16x16x32_bf16(af[a2], bx[b2], ap[a2][b2], 0, 0, 0);
    }
    #pragma unroll
    for (int a2 = 0; a2 < 2; ++a2) {
        int n = w * 32 + a2 * 16 + g * 4;
        float4 pb = *(const float4*)(proj_b + n);
        #pragma unroll
        for (int b2 = 0; b2 < 4; ++b2) {
            int t = b2 * 16 + c;
            float* dst = out + ((size_t)((b * 64 + t) * 512 + 256 + n)) * 576 + hw;
            dst[0]        = ap[a2][b2][0] + pb.x;
            dst[576]      = ap[a2][b2][1] + pb.y;
            dst[2 * 576]  = ap[a2][b2][2] + pb.z;
            dst[3 * 576]  = ap[a2][b2][3] + pb.w;
        }
    }
}

// ---------- launcher ----------
extern "C" void kernel_launch(void* const* d_in, const int* in_sizes, int n_in,
                              void* d_out, int out_size, void* d_ws, size_t ws_size,
                              hipStream_t stream) {
    (void)in_sizes; (void)n_in; (void)out_size;
    const float* x      = (const float*)d_in[0];
    const float* rpb    = (const float*)d_in[1];
    const float* qkv_w  = (const float*)d_in[2];
    const float* qkv_b  = (const float*)d_in[3];
    const float* proj_w = (const float*)d_in[4];
    const float* proj_b = (const float*)d_in[5];
    float* out = (float*)d_out;

    // ws: wq 393216 | wp 131072 | xb 37748736
    char* ws = (char*)d_ws;
    unsigned short* wq = (unsigned short*)ws;
    unsigned short* wp = (unsigned short*)(ws + 393216);
    unsigned short* xb = (unsigned short*)(ws + 524288);
    if (ws_size < (size_t)524288 + 37748736) return;

    cvt_weights<<<1024, 256, 0, stream>>>(qkv_w, proj_w, wq, wp);
    transpose_b<<<dim3(128, 9), 256, 0, stream>>>(x, xb, out);
    fused_block<<<1152, 512, 0, stream>>>(xb, wq, wp, qkv_b, proj_b, rpb, out);
}

// Round 7
// 247.448 us; speedup vs baseline: 1.0176x; 1.0176x over previous
//
#include <hip/hip_runtime.h>
#include <hip/hip_bf16.h>

// ---------- types ----------
typedef __attribute__((ext_vector_type(4))) float  f32x4;
typedef __attribute__((ext_vector_type(8))) short  bf16x8;   // 8 bf16 in 4 VGPRs
typedef __attribute__((ext_vector_type(8))) unsigned short u16x8;
typedef __attribute__((ext_vector_type(4))) unsigned short u16x4;
typedef __attribute__((ext_vector_type(4))) int i32x4;

__device__ __forceinline__ unsigned short f2bf(float f) {
    union { float f; unsigned u; } v; v.f = f;
    unsigned u = v.u;
    unsigned r = u + 0x7fffu + ((u >> 16) & 1u);   // round-to-nearest-even
    return (unsigned short)(r >> 16);
}

__device__ __forceinline__ unsigned cvtpk(float lo, float hi) {
    unsigned r;
    asm("v_cvt_pk_bf16_f32 %0, %1, %2" : "=v"(r) : "v"(lo), "v"(hi));
    return r;
}

__device__ __forceinline__ int selshfl(unsigned lo, unsigned hiw, int srcLane, bool hi) {
    int a = __shfl((int)lo, srcLane, 64);
    int b = __shfl((int)hiw, srcLane, 64);
    return hi ? b : a;
}

__device__ __forceinline__ bf16x8 mkfrag(int w0, int w1, int w2, int w3) {
    i32x4 t; t[0] = w0; t[1] = w1; t[2] = w2; t[3] = w3;
    return __builtin_bit_cast(bf16x8, t);
}

__device__ __forceinline__ void gload16(const void* g, void* l) {
    __builtin_amdgcn_global_load_lds((const __attribute__((address_space(1))) unsigned*)g,
                                     (__attribute__((address_space(3))) unsigned*)l, 16, 0, 0);
}

#define MFMA(A, B, C) __builtin_amdgcn_mfma_f32_16x16x32_bf16((A), (B), (C), 0, 0, 0)

// ---------- problem constants ----------
// B=2, T=64, CH=512, Hs=24, Ws=24, HW=576, P=1152, DIM=256, HEADS=8, HD=32
// xb layout: p-major, xb[(p*64 + t)*256 + c]

// ---------- K0: weights fp32 -> bf16 ----------
__global__ void cvt_weights(const float* __restrict__ qkv_w, const float* __restrict__ proj_w,
                            unsigned short* __restrict__ wq, unsigned short* __restrict__ wp) {
    int i = blockIdx.x * 256 + threadIdx.x;          // 262144 total
    if (i < 196608) wq[i] = f2bf(qkv_w[i]);
    else            wp[i - 196608] = f2bf(proj_w[i - 196608]);
}

// ---------- K2: transpose b-half -> xb[(p*64+t)*256 + c] bf16; also copies a-half ----------
__global__ __launch_bounds__(256) void transpose_b(const float* __restrict__ x,
                                                   unsigned short* __restrict__ xb,
                                                   float* __restrict__ outp) {
    __shared__ unsigned short tile[256][72];
    const int bt  = blockIdx.x;                       // b*64+t
    const int hw0 = blockIdx.y * 64;
    const int tid = threadIdx.x;
    // a-half copy: 256 ch x 64 hw of this slab
    {
        const size_t slab = (size_t)bt * 294912;      // 512*576
        #pragma unroll
        for (int it = 0; it < 16; ++it) {
            int idx = it * 256 + tid;
            int ch  = idx >> 4;
            int off = (idx & 15) * 4;
            size_t o = slab + (size_t)ch * 576 + hw0 + off;
            *(float4*)(outp + o) = *(const float4*)(x + o);
        }
    }
    const float* src = x + ((size_t)bt * 512 + 256) * 576 + hw0;
    const int c_sub = tid >> 4, l16 = tid & 15;
    #pragma unroll
    for (int it = 0; it < 16; ++it) {
        int cc = it * 16 + c_sub;
        const float4 v = *(const float4*)(src + (size_t)cc * 576 + l16 * 4);
        tile[cc][l16 * 4 + 0] = f2bf(v.x);
        tile[cc][l16 * 4 + 1] = f2bf(v.y);
        tile[cc][l16 * 4 + 2] = f2bf(v.z);
        tile[cc][l16 * 4 + 3] = f2bf(v.w);
    }
    __syncthreads();
    const int row = tid >> 2;                 // hw within tile
    const int cs  = (tid & 3) * 64;
    const int b = bt >> 6, t = bt & 63;
    size_t m = ((size_t)(b * 576 + hw0 + row)) * 64 + t;   // p-major
    unsigned short* dst = xb + m * 256 + cs;
    #pragma unroll
    for (int q = 0; q < 8; ++q) {
        u16x8 v;
        #pragma unroll
        for (int u = 0; u < 8; ++u) v[u] = tile[cs + q * 8 + u][row];
        *(u16x8*)(dst + q * 8) = v;
    }
}

// ================= fused-kernel helper macros (all literal indices; no aggregates) =================
#define PKPAIR(D, A, B4) \
    const unsigned D##_0 = cvtpk(A[0] + B4.x, A[1] + B4.y); \
    const unsigned D##_1 = cvtpk(A[2] + B4.z, A[3] + B4.w);

#define MKF(DST, LO, HI_) \
    DST = mkfrag(selshfl(LO##_0, HI_##_0, lA, hi), selshfl(LO##_1, HI_##_1, lA, hi), \
                 selshfl(LO##_0, HI_##_0, lB, hi), selshfl(LO##_1, HI_##_1, lB, hi));

#define SM1(SC, JT, R) { \
    const int j_ = (JT) * 16 + 4 * g + (R); \
    int d_ = j_ - i_ + 63; d_ = d_ > 63 ? 63 : d_; \
    const float v_ = SC[R] * scale + bias_w[d_]; \
    const float e_ = (j_ > i_) ? 0.f : __expf(v_); \
    SC[R] = e_; rs += e_; }

#define SMROW(SC, JT) SM1(SC, JT, 0) SM1(SC, JT, 1) SM1(SC, JT, 2) SM1(SC, JT, 3)

#define ATT_COL(IT, QF, O0V, O1V) { \
    f32x4 Sc0{0.f,0.f,0.f,0.f}, Sc1{0.f,0.f,0.f,0.f}, Sc2{0.f,0.f,0.f,0.f}, Sc3{0.f,0.f,0.f,0.f}; \
    __builtin_amdgcn_s_setprio(1); \
    Sc0 = MFMA(kf0, QF, Sc0); Sc1 = MFMA(kf1, QF, Sc1); \
    Sc2 = MFMA(kf2, QF, Sc2); Sc3 = MFMA(kf3, QF, Sc3); \
    __builtin_amdgcn_s_setprio(0); \
    const int i_ = (IT) * 16 + c; \
    float rs = 0.f; \
    SMROW(Sc0, 0) SMROW(Sc1, 1) SMROW(Sc2, 2) SMROW(Sc3, 3) \
    rs += __shfl_xor(rs, 16, 64); \
    rs += __shfl_xor(rs, 32, 64); \
    const float inv = 1.0f / rs; \
    const unsigned p00 = cvtpk(Sc0[0]*inv, Sc0[1]*inv), p01 = cvtpk(Sc0[2]*inv, Sc0[3]*inv); \
    const unsigned p10 = cvtpk(Sc1[0]*inv, Sc1[1]*inv), p11 = cvtpk(Sc1[2]*inv, Sc1[3]*inv); \
    const unsigned p20 = cvtpk(Sc2[0]*inv, Sc2[1]*inv), p21 = cvtpk(Sc2[2]*inv, Sc2[3]*inv); \
    const unsigned p30 = cvtpk(Sc3[0]*inv, Sc3[1]*inv), p31 = cvtpk(Sc3[2]*inv, Sc3[3]*inv); \
    const bf16x8 pf0 = mkfrag(selshfl(p00, p10, lA, hi), selshfl(p01, p11, lA, hi), \
                              selshfl(p00, p10, lB, hi), selshfl(p01, p11, lB, hi)); \
    const bf16x8 pf1 = mkfrag(selshfl(p20, p30, lA, hi), selshfl(p21, p31, lA, hi), \
                              selshfl(p20, p30, lB, hi), selshfl(p21, p31, lB, hi)); \
    __builtin_amdgcn_s_setprio(1); \
    O0V = MFMA(vf00, pf0, O0V); O1V = MFMA(vf10, pf0, O1V); \
    O0V = MFMA(vf01, pf1, O0V); O1V = MFMA(vf11, pf1, O1V); \
    __builtin_amdgcn_s_setprio(0); }

#define OSTORE(OV, DT, IT) { \
    const int t_ = (IT) * 16 + c; \
    const int unit_ = w * 4 + (DT) * 2 + (g >> 1); \
    u16x4 v_; v_[0] = f2bf(OV[0]); v_[1] = f2bf(OV[1]); v_[2] = f2bf(OV[2]); v_[3] = f2bf(OV[3]); \
    *(u16x4*)(&xs[t_ * 256 + ((unit_ ^ (t_ & 7)) << 3) + 4 * (g & 1)]) = v_; }

// ---------- K3: fused qkv + attention + proj, one block per pixel ----------
// 512 threads = 8 waves; wave w owns head w. LDS 78 KB -> 2 blocks/CU = 4 waves/EU.
__global__ __launch_bounds__(512, 4)
void fused_block(
    const unsigned short* __restrict__ xb,
    const unsigned short* __restrict__ wqkv,   // [768][256] bf16
    const unsigned short* __restrict__ wproj,  // [256][256] bf16
    const float* __restrict__ qkv_b,
    const float* __restrict__ proj_b,
    const float* __restrict__ rpb,
    float* __restrict__ out)
{
    __shared__ unsigned short xs[16384];        // 64 t-rows x 256 c (swizzled 16B units); reused as att
    __shared__ unsigned short VtAll[256 * 88];  // V^T[d][t], row stride 88
    __shared__ float bias_s[8][64];             // bias_s[h][d], d = j-i+63 <= 63 for unmasked

    const int tid  = threadIdx.x;
    const int lane = tid & 63, w = tid >> 6;
    const int c = lane & 15, g = lane >> 4;
    const int c7 = c & 7;
    const bool hi = g >= 2;                     // a2/jt-select for the g-group shuffle
    const int lA = c + 16 * ((2 * g) & 3);      // source lane for frag words 0,1
    const int lB = c + 16 * ((2 * g + 1) & 3);  // source lane for frag words 2,3
    const int bid = blockIdx.x;
    const int p  = (bid & 7) * 144 + (bid >> 3);   // XCD-contiguous pixels
    const int b  = p / 576, hw = p % 576;

    // ---- stage xs (32 KB), source pre-swizzled so linear LDS holds swizzled rows
    const unsigned short* src = xb + (size_t)p * 16384;
    #pragma unroll
    for (int it = 0; it < 4; ++it) {
        int U = it * 512 + tid;
        int r = U >> 5, u = U & 31;
        gload16(src + r * 256 + ((u ^ (r & 7)) << 3), &xs[U << 3]);
    }
    bias_s[tid & 7][tid >> 3] = rpb[tid];       // rows 0..63 of rpb -> [h][d]
    __syncthreads();

    const float* bias_w = bias_s[w];
    const float scale = 0.17677669529663687f;   // 1/sqrt(32)

    // ================= pass 1: V  (acc -> VtAll, own rows only) =================
    {
        f32x4 acc[2][4] = {};
        #pragma unroll
        for (int ks = 0; ks < 8; ++ks) {
            bf16x8 bx[4], af[2];
            #pragma unroll
            for (int b2 = 0; b2 < 4; ++b2)
                bx[b2] = *(const bf16x8*)(&xs[(b2 * 16 + c) * 256 + (((ks * 4 + g) ^ c7) << 3)]);
            #pragma unroll
            for (int a2 = 0; a2 < 2; ++a2)
                af[a2] = *(const bf16x8*)(wqkv + (size_t)(512 + w * 32 + a2 * 16 + c) * 256 + ks * 32 + g * 8);
            #pragma unroll
            for (int a2 = 0; a2 < 2; ++a2)
                #pragma unroll
                for (int b2 = 0; b2 < 4; ++b2)
                    acc[a2][b2] = MFMA(af[a2], bx[b2], acc[a2][b2]);
        }
        #pragma unroll
        for (int a2 = 0; a2 < 2; ++a2) {
            float4 bv = *(const float4*)(qkv_b + 512 + w * 32 + a2 * 16 + g * 4);
            #pragma unroll
            for (int b2 = 0; b2 < 4; ++b2) {
                int t = b2 * 16 + c;
                VtAll[(w * 32 + a2 * 16 + g * 4 + 0) * 88 + t] = f2bf(acc[a2][b2][0] + bv.x);
                VtAll[(w * 32 + a2 * 16 + g * 4 + 1) * 88 + t] = f2bf(acc[a2][b2][1] + bv.y);
                VtAll[(w * 32 + a2 * 16 + g * 4 + 2) * 88 + t] = f2bf(acc[a2][b2][2] + bv.z);
                VtAll[(w * 32 + a2 * 16 + g * 4 + 3) * 88 + t] = f2bf(acc[a2][b2][3] + bv.w);
            }
        }
    }

    // ================= pass 2: K and Q together -> packed regs -> fragments =================
    bf16x8 kf0, kf1, kf2, kf3, qf0, qf1, qf2, qf3;
    {
        f32x4 ak[2][4] = {}, aq[2][4] = {};
        #pragma unroll
        for (int ks = 0; ks < 8; ++ks) {
            bf16x8 bx[4], afk[2], afq[2];
            #pragma unroll
            for (int b2 = 0; b2 < 4; ++b2)
                bx[b2] = *(const bf16x8*)(&xs[(b2 * 16 + c) * 256 + (((ks * 4 + g) ^ c7) << 3)]);
            #pragma unroll
            for (int a2 = 0; a2 < 2; ++a2) {
                afk[a2] = *(const bf16x8*)(wqkv + (size_t)(256 + w * 32 + a2 * 16 + c) * 256 + ks * 32 + g * 8);
                afq[a2] = *(const bf16x8*)(wqkv + (size_t)(      w * 32 + a2 * 16 + c) * 256 + ks * 32 + g * 8);
            }
            #pragma unroll
            for (int a2 = 0; a2 < 2; ++a2)
                #pragma unroll
                for (int b2 = 0; b2 < 4; ++b2) {
                    ak[a2][b2] = MFMA(afk[a2], bx[b2], ak[a2][b2]);
                    aq[a2][b2] = MFMA(afq[a2], bx[b2], aq[a2][b2]);
                }
        }
        const float4 bk0 = *(const float4*)(qkv_b + 256 + w * 32 + g * 4);
        const float4 bk1 = *(const float4*)(qkv_b + 256 + w * 32 + 16 + g * 4);
        const float4 bq0 = *(const float4*)(qkv_b +       w * 32 + g * 4);
        const float4 bq1 = *(const float4*)(qkv_b +       w * 32 + 16 + g * 4);
        PKPAIR(kp00, ak[0][0], bk0) PKPAIR(kp01, ak[0][1], bk0)
        PKPAIR(kp02, ak[0][2], bk0) PKPAIR(kp03, ak[0][3], bk0)
        PKPAIR(kp10, ak[1][0], bk1) PKPAIR(kp11, ak[1][1], bk1)
        PKPAIR(kp12, ak[1][2], bk1) PKPAIR(kp13, ak[1][3], bk1)
        PKPAIR(qp00, aq[0][0], bq0) PKPAIR(qp01, aq[0][1], bq0)
        PKPAIR(qp02, aq[0][2], bq0) PKPAIR(qp03, aq[0][3], bq0)
        PKPAIR(qp10, aq[1][0], bq1) PKPAIR(qp11, aq[1][1], bq1)
        PKPAIR(qp12, aq[1][2], bq1) PKPAIR(qp13, aq[1][3], bq1)
        MKF(kf0, kp00, kp10) MKF(kf1, kp01, kp11) MKF(kf2, kp02, kp12) MKF(kf3, kp03, kp13)
        MKF(qf0, qp00, qp10) MKF(qf1, qp01, qp11) MKF(qf2, qp02, qp12) MKF(qf3, qp03, qp13)
    }

    // ---- V^T fragments (wave-local rows; same-wave ds_write->ds_read, no barrier needed) ----
    const bf16x8 vf00 = *(const bf16x8*)(&VtAll[(w * 32 +  0 + c) * 88 +  0 + g * 8]);
    const bf16x8 vf01 = *(const bf16x8*)(&VtAll[(w * 32 +  0 + c) * 88 + 32 + g * 8]);
    const bf16x8 vf10 = *(const bf16x8*)(&VtAll[(w * 32 + 16 + c) * 88 +  0 + g * 8]);
    const bf16x8 vf11 = *(const bf16x8*)(&VtAll[(w * 32 + 16 + c) * 88 + 32 + g * 8]);

    // ================= per-column QK^T -> softmax -> PV =================
    f32x4 O00{0.f,0.f,0.f,0.f}, O01{0.f,0.f,0.f,0.f}, O02{0.f,0.f,0.f,0.f}, O03{0.f,0.f,0.f,0.f};
    f32x4 O10{0.f,0.f,0.f,0.f}, O11{0.f,0.f,0.f,0.f}, O12{0.f,0.f,0.f,0.f}, O13{0.f,0.f,0.f,0.f};
    ATT_COL(0, qf0, O00, O10)
    ATT_COL(1, qf1, O01, O11)
    ATT_COL(2, qf2, O02, O12)
    ATT_COL(3, qf3, O03, O13)

    __syncthreads();   // all waves done reading xs
    // ---- O -> att (xs region, swizzled units), packed u16x4 along d ----
    OSTORE(O00, 0, 0) OSTORE(O01, 0, 1) OSTORE(O02, 0, 2) OSTORE(O03, 0, 3)
    OSTORE(O10, 1, 0) OSTORE(O11, 1, 1) OSTORE(O12, 1, 2) OSTORE(O13, 1, 3)
    __syncthreads();

    // ================= proj: D[n][t], A = Wp rows (wave's 32 n), B = att rows =================
    f32x4 ap[2][4] = {};
    #pragma unroll
    for (int ks = 0; ks < 8; ++ks) {
        bf16x8 af[2], bx[4];
        #pragma unroll
        for (int a2 = 0; a2 < 2; ++a2)
            af[a2] = *(const bf16x8*)(wproj + (size_t)(w * 32 + a2 * 16 + c) * 256 + ks * 32 + g * 8);
        #pragma unroll
        for (int b2 = 0; b2 < 4; ++b2)
            bx[b2] = *(const bf16x8*)(&xs[(b2 * 16 + c) * 256 + (((ks * 4 + g) ^ c7) << 3)]);
        #pragma unroll
        for (int a2 = 0; a2 < 2; ++a2)
            #pragma unroll
            for (int b2 = 0; b2 < 4; ++b2)
                ap[a2][b2] = MFMA(af[a2], bx[b2], ap[a2][b2]);
    }
    #pragma unroll
    for (int a2 = 0; a2 < 2; ++a2) {
        int n = w * 32 + a2 * 16 + g * 4;
        float4 pb = *(const float4*)(proj_b + n);
        #pragma unroll
        for (int b2 = 0; b2 < 4; ++b2) {
            int t = b2 * 16 + c;
            float* dst = out + ((size_t)((b * 64 + t) * 512 + 256 + n)) * 576 + hw;
            dst[0]        = ap[a2][b2][0] + pb.x;
            dst[576]      = ap[a2][b2][1] + pb.y;
            dst[2 * 576]  = ap[a2][b2][2] + pb.z;
            dst[3 * 576]  = ap[a2][b2][3] + pb.w;
        }
    }
}

// ---------- launcher ----------
extern "C" void kernel_launch(void* const* d_in, const int* in_sizes, int n_in,
                              void* d_out, int out_size, void* d_ws, size_t ws_size,
                              hipStream_t stream) {
    (void)in_sizes; (void)n_in; (void)out_size;
    const float* x      = (const float*)d_in[0];
    const float* rpb    = (const float*)d_in[1];
    const float* qkv_w  = (const float*)d_in[2];
    const float* qkv_b  = (const float*)d_in[3];
    const float* proj_w = (const float*)d_in[4];
    const float* proj_b = (const float*)d_in[5];
    float* out = (float*)d_out;

    // ws: wq 393216 | wp 131072 | xb 37748736
    char* ws = (char*)d_ws;
    unsigned short* wq = (unsigned short*)ws;
    unsigned short* wp = (unsigned short*)(ws + 393216);
    unsigned short* xb = (unsigned short*)(ws + 524288);
    if (ws_size < (size_t)524288 + 37748736) return;

    cvt_weights<<<1024, 256, 0, stream>>>(qkv_w, proj_w, wq, wp);
    transpose_b<<<dim3(128, 9), 256, 0, stream>>>(x, xb, out);
    fused_block<<<1152, 512, 0, stream>>>(xb, wq, wp, qkv_b, proj_b, rpb, out);
}

// Round 8
// 227.496 us; speedup vs baseline: 1.1068x; 1.0877x over previous
//
#include <hip/hip_runtime.h>
#include <hip/hip_bf16.h>

// ---------- types ----------
typedef __attribute__((ext_vector_type(4))) float  f32x4;
typedef __attribute__((ext_vector_type(8))) short  bf16x8;   // 8 bf16 in 4 VGPRs
typedef __attribute__((ext_vector_type(8))) unsigned short u16x8;
typedef __attribute__((ext_vector_type(4))) unsigned short u16x4;
typedef __attribute__((ext_vector_type(4))) int i32x4;

__device__ __forceinline__ unsigned short f2bf(float f) {
    union { float f; unsigned u; } v; v.f = f;
    unsigned u = v.u;
    unsigned r = u + 0x7fffu + ((u >> 16) & 1u);   // round-to-nearest-even
    return (unsigned short)(r >> 16);
}

__device__ __forceinline__ unsigned cvtpk(float lo, float hi) {
    unsigned r;
    asm("v_cvt_pk_bf16_f32 %0, %1, %2" : "=v"(r) : "v"(lo), "v"(hi));
    return r;
}

__device__ __forceinline__ int selshfl(unsigned lo, unsigned hiw, int srcLane, bool hi) {
    int a = __shfl((int)lo, srcLane, 64);
    int b = __shfl((int)hiw, srcLane, 64);
    return hi ? b : a;
}

__device__ __forceinline__ bf16x8 mkfrag(int w0, int w1, int w2, int w3) {
    i32x4 t; t[0] = w0; t[1] = w1; t[2] = w2; t[3] = w3;
    return __builtin_bit_cast(bf16x8, t);
}

__device__ __forceinline__ void gload16(const void* g, void* l) {
    __builtin_amdgcn_global_load_lds((const __attribute__((address_space(1))) unsigned*)g,
                                     (__attribute__((address_space(3))) unsigned*)l, 16, 0, 0);
}

#define MFMA(A, B, C) __builtin_amdgcn_mfma_f32_16x16x32_bf16((A), (B), (C), 0, 0, 0)

// ---------- problem constants ----------
// B=2, T=64, CH=512, Hs=24, Ws=24, HW=576, P=1152, DIM=256, HEADS=8, HD=32
// xb layout: p-major, xb[(p*64 + t)*256 + c]
// att layout: att[(t*1152 + p)*256 + ch]   (m = t*1152+p, matches gemm_proj)

// ---------- K0: weights fp32 -> bf16 ----------
__global__ void cvt_weights(const float* __restrict__ qkv_w, const float* __restrict__ proj_w,
                            unsigned short* __restrict__ wq, unsigned short* __restrict__ wp) {
    int i = blockIdx.x * 256 + threadIdx.x;          // 262144 total
    if (i < 196608) wq[i] = f2bf(qkv_w[i]);
    else            wp[i - 196608] = f2bf(proj_w[i - 196608]);
}

// ---------- K1: transpose b-half -> xb[(p*64+t)*256 + c] bf16; also copies a-half ----------
__global__ __launch_bounds__(256) void transpose_b(const float* __restrict__ x,
                                                   unsigned short* __restrict__ xb,
                                                   float* __restrict__ outp) {
    __shared__ unsigned short tile[256][72];
    const int bt  = blockIdx.x;                       // b*64+t
    const int hw0 = blockIdx.y * 64;
    const int tid = threadIdx.x;
    {   // a-half copy: 256 ch x 64 hw of this slab
        const size_t slab = (size_t)bt * 294912;      // 512*576
        #pragma unroll
        for (int it = 0; it < 16; ++it) {
            int idx = it * 256 + tid;
            int ch  = idx >> 4;
            int off = (idx & 15) * 4;
            size_t o = slab + (size_t)ch * 576 + hw0 + off;
            *(float4*)(outp + o) = *(const float4*)(x + o);
        }
    }
    const float* src = x + ((size_t)bt * 512 + 256) * 576 + hw0;
    const int c_sub = tid >> 4, l16 = tid & 15;
    #pragma unroll
    for (int it = 0; it < 16; ++it) {
        int cc = it * 16 + c_sub;
        const float4 v = *(const float4*)(src + (size_t)cc * 576 + l16 * 4);
        tile[cc][l16 * 4 + 0] = f2bf(v.x);
        tile[cc][l16 * 4 + 1] = f2bf(v.y);
        tile[cc][l16 * 4 + 2] = f2bf(v.z);
        tile[cc][l16 * 4 + 3] = f2bf(v.w);
    }
    __syncthreads();
    const int row = tid >> 2;                 // hw within tile
    const int cs  = (tid & 3) * 64;
    const int b = bt >> 6, t = bt & 63;
    size_t m = ((size_t)(b * 576 + hw0 + row)) * 64 + t;   // p-major
    unsigned short* dst = xb + m * 256 + cs;
    #pragma unroll
    for (int q = 0; q < 8; ++q) {
        u16x8 v;
        #pragma unroll
        for (int u = 0; u < 8; ++u) v[u] = tile[cs + q * 8 + u][row];
        *(u16x8*)(dst + q * 8) = v;
    }
}

// ================= attention helper macros (all literal indices) =================
#define PKPAIR(D, A, B4) \
    const unsigned D##_0 = cvtpk(A[0] + B4.x, A[1] + B4.y); \
    const unsigned D##_1 = cvtpk(A[2] + B4.z, A[3] + B4.w);

#define MKF(DST, LO, HI_) \
    DST = mkfrag(selshfl(LO##_0, HI_##_0, lA, hi), selshfl(LO##_1, HI_##_1, lA, hi), \
                 selshfl(LO##_0, HI_##_0, lB, hi), selshfl(LO##_1, HI_##_1, lB, hi));

#define SM1(SC, JT, R) { \
    const int j_ = (JT) * 16 + 4 * g + (R); \
    int d_ = j_ - i_ + 63; d_ = d_ > 63 ? 63 : d_; \
    const float v_ = SC[R] * scale + bias_w[d_]; \
    const float e_ = (j_ > i_) ? 0.f : __expf(v_); \
    SC[R] = e_; rs += e_; }

#define SMROW(SC, JT) SM1(SC, JT, 0) SM1(SC, JT, 1) SM1(SC, JT, 2) SM1(SC, JT, 3)

#define ATT_COL(IT, QF, O0V, O1V) { \
    f32x4 Sc0{0.f,0.f,0.f,0.f}, Sc1{0.f,0.f,0.f,0.f}, Sc2{0.f,0.f,0.f,0.f}, Sc3{0.f,0.f,0.f,0.f}; \
    Sc0 = MFMA(kf0, QF, Sc0); Sc1 = MFMA(kf1, QF, Sc1); \
    Sc2 = MFMA(kf2, QF, Sc2); Sc3 = MFMA(kf3, QF, Sc3); \
    const int i_ = (IT) * 16 + c; \
    float rs = 0.f; \
    SMROW(Sc0, 0) SMROW(Sc1, 1) SMROW(Sc2, 2) SMROW(Sc3, 3) \
    rs += __shfl_xor(rs, 16, 64); \
    rs += __shfl_xor(rs, 32, 64); \
    const float inv = 1.0f / rs; \
    const unsigned p00 = cvtpk(Sc0[0]*inv, Sc0[1]*inv), p01 = cvtpk(Sc0[2]*inv, Sc0[3]*inv); \
    const unsigned p10 = cvtpk(Sc1[0]*inv, Sc1[1]*inv), p11 = cvtpk(Sc1[2]*inv, Sc1[3]*inv); \
    const unsigned p20 = cvtpk(Sc2[0]*inv, Sc2[1]*inv), p21 = cvtpk(Sc2[2]*inv, Sc2[3]*inv); \
    const unsigned p30 = cvtpk(Sc3[0]*inv, Sc3[1]*inv), p31 = cvtpk(Sc3[2]*inv, Sc3[3]*inv); \
    const bf16x8 pf0 = mkfrag(selshfl(p00, p10, lA, hi), selshfl(p01, p11, lA, hi), \
                              selshfl(p00, p10, lB, hi), selshfl(p01, p11, lB, hi)); \
    const bf16x8 pf1 = mkfrag(selshfl(p20, p30, lA, hi), selshfl(p21, p31, lA, hi), \
                              selshfl(p20, p30, lB, hi), selshfl(p21, p31, lB, hi)); \
    O0V = MFMA(vf00, pf0, O0V); O1V = MFMA(vf10, pf0, O1V); \
    O0V = MFMA(vf01, pf1, O0V); O1V = MFMA(vf11, pf1, O1V); }

#define OSTOREG(OV, DT, IT) { \
    const int t_ = (IT) * 16 + c; \
    u16x4 v_; v_[0] = f2bf(OV[0]); v_[1] = f2bf(OV[1]); v_[2] = f2bf(OV[2]); v_[3] = f2bf(OV[3]); \
    *(u16x4*)(att + ((size_t)(t_ * 1152 + p)) * 256 + h * 32 + (DT) * 16 + 4 * g) = v_; }

// ---------- K2: attention, ONE INDEPENDENT WAVE per (pixel, head) ----------
// 2304 blocks x 256 threads (4 waves). gw = bid*4+w; h = gw/1152, p = gw%1152.
// Same-pixel waves share bid%8 (1152%8==0) -> same XCD -> xb L2-shared.
// No __syncthreads in the hot path; each wave has a private LDS V scratch.
__global__ __launch_bounds__(256, 3)
void attn_heads(
    const unsigned short* __restrict__ xb,
    const unsigned short* __restrict__ wqkv,   // [768][256] bf16
    const float* __restrict__ qkv_b,
    const float* __restrict__ rpb,
    unsigned short* __restrict__ att)
{
    __shared__ unsigned short vt[4][32 * 88];   // per-wave V^T[d][t], stride 88
    __shared__ float bias_s[8][64];             // bias_s[h][d], d = j-i+63

    const int tid  = threadIdx.x;
    const int lane = tid & 63, w = tid >> 6;
    const int c = lane & 15, g = lane >> 4;
    const bool hi = g >= 2;
    const int lA = c + 16 * ((2 * g) & 3);
    const int lB = c + 16 * ((2 * g + 1) & 3);

    bias_s[tid & 7][tid >> 3] = rpb[tid];
    bias_s[(tid + 256) & 7][(tid + 256) >> 3] = rpb[tid + 256];
    __syncthreads();   // bias table only (once, before the independent phase)

    const int gw = blockIdx.x * 4 + w;
    const int h  = gw / 1152;
    const int p  = gw - h * 1152;
    const float* bias_w = bias_s[h];
    const float scale = 0.17677669529663687f;   // 1/sqrt(32)
    const unsigned short* xrow = xb + (size_t)p * 16384;
    unsigned short* vts = vt[w];

    // ---- merged QKV accumulation: D[n][t] per matrix, all in registers ----
    f32x4 aq[2][4] = {}, ak[2][4] = {}, av[2][4] = {};
    #pragma unroll
    for (int ks = 0; ks < 8; ++ks) {
        bf16x8 bx[4];
        #pragma unroll
        for (int b2 = 0; b2 < 4; ++b2)
            bx[b2] = *(const bf16x8*)(xrow + (b2 * 16 + c) * 256 + ks * 32 + g * 8);
        #pragma unroll
        for (int a2 = 0; a2 < 2; ++a2) {
            const size_t ko = (size_t)ks * 32 + g * 8;
            const bf16x8 fq = *(const bf16x8*)(wqkv + (size_t)(      h * 32 + a2 * 16 + c) * 256 + ko);
            const bf16x8 fk = *(const bf16x8*)(wqkv + (size_t)(256 + h * 32 + a2 * 16 + c) * 256 + ko);
            const bf16x8 fv = *(const bf16x8*)(wqkv + (size_t)(512 + h * 32 + a2 * 16 + c) * 256 + ko);
            #pragma unroll
            for (int b2 = 0; b2 < 4; ++b2) {
                aq[a2][b2] = MFMA(fq, bx[b2], aq[a2][b2]);
                ak[a2][b2] = MFMA(fk, bx[b2], ak[a2][b2]);
                av[a2][b2] = MFMA(fv, bx[b2], av[a2][b2]);
            }
        }
    }

    // ---- V -> per-wave LDS scratch (same-wave write->read, waitcnt only) ----
    #pragma unroll
    for (int a2 = 0; a2 < 2; ++a2) {
        float4 bv = *(const float4*)(qkv_b + 512 + h * 32 + a2 * 16 + g * 4);
        #pragma unroll
        for (int b2 = 0; b2 < 4; ++b2) {
            int t = b2 * 16 + c;
            vts[(a2 * 16 + g * 4 + 0) * 88 + t] = f2bf(av[a2][b2][0] + bv.x);
            vts[(a2 * 16 + g * 4 + 1) * 88 + t] = f2bf(av[a2][b2][1] + bv.y);
            vts[(a2 * 16 + g * 4 + 2) * 88 + t] = f2bf(av[a2][b2][2] + bv.z);
            vts[(a2 * 16 + g * 4 + 3) * 88 + t] = f2bf(av[a2][b2][3] + bv.w);
        }
    }

    // ---- K,Q pack -> fragments (in-register lane redistribution) ----
    bf16x8 kf0, kf1, kf2, kf3, qf0, qf1, qf2, qf3;
    {
        const float4 bk0 = *(const float4*)(qkv_b + 256 + h * 32 + g * 4);
        const float4 bk1 = *(const float4*)(qkv_b + 256 + h * 32 + 16 + g * 4);
        const float4 bq0 = *(const float4*)(qkv_b +       h * 32 + g * 4);
        const float4 bq1 = *(const float4*)(qkv_b +       h * 32 + 16 + g * 4);
        PKPAIR(kp00, ak[0][0], bk0) PKPAIR(kp01, ak[0][1], bk0)
        PKPAIR(kp02, ak[0][2], bk0) PKPAIR(kp03, ak[0][3], bk0)
        PKPAIR(kp10, ak[1][0], bk1) PKPAIR(kp11, ak[1][1], bk1)
        PKPAIR(kp12, ak[1][2], bk1) PKPAIR(kp13, ak[1][3], bk1)
        PKPAIR(qp00, aq[0][0], bq0) PKPAIR(qp01, aq[0][1], bq0)
        PKPAIR(qp02, aq[0][2], bq0) PKPAIR(qp03, aq[0][3], bq0)
        PKPAIR(qp10, aq[1][0], bq1) PKPAIR(qp11, aq[1][1], bq1)
        PKPAIR(qp12, aq[1][2], bq1) PKPAIR(qp13, aq[1][3], bq1)
        MKF(kf0, kp00, kp10) MKF(kf1, kp01, kp11) MKF(kf2, kp02, kp12) MKF(kf3, kp03, kp13)
        MKF(qf0, qp00, qp10) MKF(qf1, qp01, qp11) MKF(qf2, qp02, qp12) MKF(qf3, qp03, qp13)
    }

    // ---- V^T fragments from scratch ----
    const bf16x8 vf00 = *(const bf16x8*)(&vts[( 0 + c) * 88 +  0 + g * 8]);
    const bf16x8 vf01 = *(const bf16x8*)(&vts[( 0 + c) * 88 + 32 + g * 8]);
    const bf16x8 vf10 = *(const bf16x8*)(&vts[(16 + c) * 88 +  0 + g * 8]);
    const bf16x8 vf11 = *(const bf16x8*)(&vts[(16 + c) * 88 + 32 + g * 8]);

    // ---- per-column QK^T -> softmax -> PV ----
    f32x4 O00{0.f,0.f,0.f,0.f}, O01{0.f,0.f,0.f,0.f}, O02{0.f,0.f,0.f,0.f}, O03{0.f,0.f,0.f,0.f};
    f32x4 O10{0.f,0.f,0.f,0.f}, O11{0.f,0.f,0.f,0.f}, O12{0.f,0.f,0.f,0.f}, O13{0.f,0.f,0.f,0.f};
    ATT_COL(0, qf0, O00, O10)
    ATT_COL(1, qf1, O01, O11)
    ATT_COL(2, qf2, O02, O12)
    ATT_COL(3, qf3, O03, O13)

    // ---- O -> att workspace (u16x4 along d) ----
    OSTOREG(O00, 0, 0) OSTOREG(O01, 0, 1) OSTOREG(O02, 0, 2) OSTOREG(O03, 0, 3)
    OSTOREG(O10, 1, 0) OSTOREG(O11, 1, 1) OSTOREG(O12, 1, 2) OSTOREG(O13, 1, 3)
}

// ---------- K3: proj GEMM (M=73728, N=256, K=256) + scatter to output ----------
__global__ __launch_bounds__(256, 4) void gemm_proj(const unsigned short* __restrict__ A,   // att
                                                    const unsigned short* __restrict__ Wt,  // proj w
                                                    const float* __restrict__ bias,
                                                    float* __restrict__ out) {
    __shared__ unsigned short Ws[128 * 64];
    __shared__ unsigned short Xs[128 * 64];
    const int m0 = blockIdx.x * 128, n0 = blockIdx.y * 128;
    const int tid = threadIdx.x;
    const int lane = tid & 63, w = tid >> 6;
    const int wy = w >> 1, wx = w & 1;
    const int c = lane & 15, g = lane >> 4;
    const int lr = lane >> 3, lu = lane & 7;
    const int su = lu ^ lr;
    const int cs7 = c & 7;
    f32x4 acc[4][4] = {};
    for (int k0 = 0; k0 < 256; k0 += 64) {
        #pragma unroll
        for (int q = 0; q < 4; ++q) {
            int R = w * 32 + q * 8;
            gload16(Wt + (size_t)(n0 + R + lr) * 256 + k0 + su * 8, &Ws[R * 64]);
            gload16(A  + (size_t)(m0 + R + lr) * 256 + k0 + su * 8, &Xs[R * 64]);
        }
        __syncthreads();
        #pragma unroll
        for (int kk = 0; kk < 2; ++kk) {
            bf16x8 af[4], bx[4];
            #pragma unroll
            for (int a2 = 0; a2 < 4; ++a2)
                af[a2] = *(const bf16x8*)(&Ws[(wy * 64 + a2 * 16 + c) * 64 + (((kk * 4 + g) ^ cs7) * 8)]);
            #pragma unroll
            for (int b2 = 0; b2 < 4; ++b2)
                bx[b2] = *(const bf16x8*)(&Xs[(wx * 64 + b2 * 16 + c) * 64 + (((kk * 4 + g) ^ cs7) * 8)]);
            #pragma unroll
            for (int a2 = 0; a2 < 4; ++a2)
                #pragma unroll
                for (int b2 = 0; b2 < 4; ++b2)
                    acc[a2][b2] = MFMA(af[a2], bx[b2], acc[a2][b2]);
        }
        __syncthreads();
    }
    // epilogue: D[n][m], m = t*1152 + b*576 + hw; 16 lanes (c) -> consecutive hw floats
    #pragma unroll
    for (int a2 = 0; a2 < 4; ++a2) {
        int n = n0 + wy * 64 + a2 * 16 + g * 4;
        float4 bv = *(const float4*)(bias + n);
        #pragma unroll
        for (int b2 = 0; b2 < 4; ++b2) {
            int m = m0 + wx * 64 + b2 * 16 + c;
            int t   = m / 1152;
            int rem = m % 1152;
            int bb  = rem / 576;
            int hw  = rem % 576;
            float* dst = out + ((size_t)(bb * 64 + t) * 512 + 256 + n) * 576 + hw;
            dst[0]        = acc[a2][b2][0] + bv.x;
            dst[576]      = acc[a2][b2][1] + bv.y;
            dst[2 * 576]  = acc[a2][b2][2] + bv.z;
            dst[3 * 576]  = acc[a2][b2][3] + bv.w;
        }
    }
}

// ---------- launcher ----------
extern "C" void kernel_launch(void* const* d_in, const int* in_sizes, int n_in,
                              void* d_out, int out_size, void* d_ws, size_t ws_size,
                              hipStream_t stream) {
    (void)in_sizes; (void)n_in; (void)out_size;
    const float* x      = (const float*)d_in[0];
    const float* rpb    = (const float*)d_in[1];
    const float* qkv_w  = (const float*)d_in[2];
    const float* qkv_b  = (const float*)d_in[3];
    const float* proj_w = (const float*)d_in[4];
    const float* proj_b = (const float*)d_in[5];
    float* out = (float*)d_out;

    // ws: wq 393216 | wp 131072 | xb 37748736 | att 37748736
    char* ws = (char*)d_ws;
    unsigned short* wq  = (unsigned short*)ws;
    unsigned short* wp  = (unsigned short*)(ws + 393216);
    unsigned short* xb  = (unsigned short*)(ws + 524288);
    unsigned short* att = (unsigned short*)(ws + 524288 + 37748736);
    if (ws_size < (size_t)524288 + 2 * 37748736) return;

    cvt_weights<<<1024, 256, 0, stream>>>(qkv_w, proj_w, wq, wp);
    transpose_b<<<dim3(128, 9), 256, 0, stream>>>(x, xb, out);
    attn_heads<<<2304, 256, 0, stream>>>(xb, wq, qkv_b, rpb, att);
    gemm_proj<<<dim3(576, 2), 256, 0, stream>>>(att, wp, proj_b, out);
}